// Round 3
// baseline (1655.474 us; speedup 1.0000x reference)
//
#include <hip/hip_runtime.h>
#include <hip/hip_bf16.h>

// Problem constants (match reference)
#define DIMT 300      // TERM_DIM
#define DPAD 320      // padded to 32
#define NRELS 40
#define RELD 5
#define TILE_M 64     // elements per chunk/workgroup
#define MAX_CHUNKS 8192  // >= 40 + ceil(500000/64) = 7853

typedef __attribute__((ext_vector_type(8))) short bf16x8;
typedef __attribute__((ext_vector_type(4))) float f32x4;

// ---------------- workspace layout (ints) ----------------
#define DESC_OFF 256
#define SORTED_OFF (DESC_OFF + 3*MAX_CHUNKS)
#define MT_OFF_BYTES(B) ((((size_t)(SORTED_OFF + (B)) * 4) + 255) & ~(size_t)255)

__global__ void k_init(int* cnt) {
    int t = threadIdx.x;
    if (t < 64) cnt[t] = 0;
    if (t < 64) cnt[64 + t] = 0;
    if (t == 0) cnt[128] = 0;
}

__global__ void k_hist(const int* __restrict__ rels, int n, int* cnt) {
    __shared__ int l[NRELS];
    int t = threadIdx.x;
    if (t < NRELS) l[t] = 0;
    __syncthreads();
    int b = blockIdx.x * 256 + t;
    if (b < n) atomicAdd(&l[rels[b]], 1);
    __syncthreads();
    if (t < NRELS && l[t]) atomicAdd(&cnt[t], l[t]);
}

__global__ void k_scan(const int* __restrict__ cnt, int* cursor, int* n_chunks,
                       int* desc_rel, int* desc_start, int* desc_end) {
    __shared__ int offs[NRELS + 1];
    __shared__ int coff[NRELS + 1];
    if (threadIdx.x == 0) {
        int s = 0, c = 0;
        for (int r = 0; r < NRELS; r++) {
            offs[r] = s; s += cnt[r];
            coff[r] = c; c += (cnt[r] + TILE_M - 1) / TILE_M;
        }
        offs[NRELS] = s; coff[NRELS] = c;
        *n_chunks = c;
    }
    __syncthreads();
    if (threadIdx.x < NRELS) cursor[threadIdx.x] = offs[threadIdx.x];
    for (int r = 0; r < NRELS; r++) {
        int nch = (cnt[r] + TILE_M - 1) / TILE_M;
        int cend = offs[r] + cnt[r];
        for (int c = threadIdx.x; c < nch; c += 256) {
            int st = offs[r] + c * TILE_M;
            desc_rel[coff[r] + c] = r;
            desc_start[coff[r] + c] = st;
            desc_end[coff[r] + c] = min(st + TILE_M, cend);
        }
    }
}

__global__ void k_scatter(const int* __restrict__ rels, int n, int* cursor,
                          int* __restrict__ sorted) {
    __shared__ int l[NRELS];
    __shared__ int base[NRELS];
    int t = threadIdx.x;
    if (t < NRELS) l[t] = 0;
    __syncthreads();
    int b = blockIdx.x * 256 + t;
    int r = -1, loc = 0;
    if (b < n) { r = rels[b]; loc = atomicAdd(&l[r], 1); }
    __syncthreads();
    if (t < NRELS && l[t]) base[t] = atomicAdd(&cursor[t], l[t]);
    __syncthreads();
    if (b < n) sorted[base[r] + loc] = b;
}

// Mt[r][n][j] = sum_i rel_table[r,i] * assoc[i][j][n], zero-padded to 320x320.
__global__ void k_build_mt(const float* __restrict__ rel_table,
                           const float* __restrict__ assoc,
                           __hip_bfloat16* __restrict__ Mt) {
    int r = blockIdx.x / 100;
    int t6 = blockIdx.x % 100;
    int tn = (t6 / 10) * 32, tj = (t6 % 10) * 32;
    __shared__ float tile[32][33];
    __shared__ float rw[RELD];
    if (threadIdx.x < RELD) rw[threadIdx.x] = rel_table[r * RELD + threadIdx.x];
    __syncthreads();
    for (int e = threadIdx.x; e < 1024; e += 256) {
        int jl = e >> 5, nl = e & 31;
        int j = tj + jl, n = tn + nl;
        float v = 0.f;
        if (j < DIMT && n < DIMT) {
            #pragma unroll
            for (int i = 0; i < RELD; i++) v += rw[i] * assoc[(i * DIMT + j) * DIMT + n];
        }
        tile[jl][nl] = v;
    }
    __syncthreads();
    for (int e = threadIdx.x; e < 1024; e += 256) {
        int nl = e >> 5, jl = e & 31;
        int n = tn + nl, j = tj + jl;
        Mt[((size_t)r * DPAD + n) * DPAD + j] = __float2bfloat16(tile[jl][nl]);
    }
}

// Grouped GEMM, barrier-free K-loop:
//   X[m,n] = sum_j tL[m][j] * M[j][n]  (bf16 MFMA, fp32 acc)
//   energy[m] = sum_n X[m,n] * tR[m][n]  (fp32 epilogue)
// A (tL rows) lives in registers for the whole K-loop (wave w owns rows
// w*16..w*16+15). B-frags are read DIRECTLY from global (Mt is L2/L3
// resident; the per-kc 20 KB B working set fits L1, absorbing the 4x
// inter-wave redundancy; the wave access pattern is 64-B-line dense).
// No LDS tile, no K-loop barriers: waves never collectively stall.
__global__ __launch_bounds__(256, 3) void k_gemm(
    const int* __restrict__ sorted, const int* __restrict__ desc_rel,
    const int* __restrict__ desc_start, const int* __restrict__ desc_end,
    const int* __restrict__ n_chunks,
    const int* __restrict__ terms_L, const int* __restrict__ terms_R,
    const float* __restrict__ term_table, const __hip_bfloat16* __restrict__ Mt,
    float* __restrict__ out) {
    int cid = blockIdx.x;
    if (cid >= *n_chunks) return;
    int rel = desc_rel[cid];
    int start = desc_start[cid];
    int tm = desc_end[cid] - start;

    __shared__ int elds[TILE_M];
    int t = threadIdx.x;
    if (t < TILE_M) elds[t] = (t < tm) ? sorted[start + t] : -1;
    __syncthreads();

    int wave = t >> 6, lane = t & 63;
    int quad = lane >> 4, l16 = lane & 15;

    const __hip_bfloat16* Mtr = Mt + (size_t)rel * DPAD * DPAD;
    // per-lane B base: row l16 (+ nt*16 rows), col quad*8 (+ kc*32)
    const __hip_bfloat16* bbase = Mtr + (size_t)l16 * DPAD + quad * 8;

    // ---- A preload: lane holds row elds[wave*16+l16], cols quad*8.. for all 10 kc ----
    int arow = wave * 16 + l16;
    int ae = elds[arow];
    const float* arp = (ae >= 0) ? (term_table + (size_t)terms_L[ae] * DIMT) : nullptr;
    bf16x8 afrag[10];
    #pragma unroll
    for (int kc = 0; kc < 10; kc++) {
        int kb = kc * 32 + quad * 8;
        float v[8];
        if (arp && kb + 8 <= DIMT) {
            float4 p0 = *(const float4*)(arp + kb);
            float4 p1 = *(const float4*)(arp + kb + 4);
            v[0] = p0.x; v[1] = p0.y; v[2] = p0.z; v[3] = p0.w;
            v[4] = p1.x; v[5] = p1.y; v[6] = p1.z; v[7] = p1.w;
        } else if (arp) {
            #pragma unroll
            for (int j = 0; j < 8; j++) v[j] = (kb + j < DIMT) ? arp[kb + j] : 0.f;
        } else {
            #pragma unroll
            for (int j = 0; j < 8; j++) v[j] = 0.f;
        }
        union { bf16x8 v8; __hip_bfloat16 h[8]; } u;
        #pragma unroll
        for (int j = 0; j < 8; j++) u.h[j] = __float2bfloat16(v[j]);
        afrag[kc] = u.v8;
    }

    f32x4 acc[20];
    #pragma unroll
    for (int i = 0; i < 20; i++) acc[i] = (f32x4){0.f, 0.f, 0.f, 0.f};

    // ---- K loop: fully unrolled, barrier-free, B direct from L1/L2 ----
    // Grouped 5 loads + 5 MFMA to bound live B registers.
    #pragma unroll
    for (int kc = 0; kc < 10; kc++) {
        #pragma unroll
        for (int g = 0; g < 4; g++) {
            bf16x8 bf[5];
            #pragma unroll
            for (int i = 0; i < 5; i++) {
                int nt = g * 5 + i;
                bf[i] = *((const bf16x8*)(bbase + nt * (16 * DPAD) + kc * 32));
            }
            #pragma unroll
            for (int i = 0; i < 5; i++) {
                acc[g * 5 + i] = __builtin_amdgcn_mfma_f32_16x16x32_bf16(
                    afrag[kc], bf[i], acc[g * 5 + i], 0, 0, 0);
            }
        }
    }

    // Epilogue: lane holds X[row=quad*4+reg][col=l16] per n-tile.
    #pragma unroll
    for (int reg = 0; reg < 4; reg++) {
        int mrow = wave * 16 + quad * 4 + reg;
        int e = elds[mrow];
        float s = 0.f;
        if (e >= 0) {
            const float* tr = term_table + (size_t)terms_R[e] * DIMT;
            #pragma unroll
            for (int nt = 0; nt < 20; nt++) {
                int n = nt * 16 + l16;
                if (n < DIMT) s += acc[nt][reg] * tr[n];
            }
        }
        s += __shfl_xor(s, 1);
        s += __shfl_xor(s, 2);
        s += __shfl_xor(s, 4);
        s += __shfl_xor(s, 8);
        if (l16 == 0 && e >= 0) out[e] = s;
    }
}

extern "C" void kernel_launch(void* const* d_in, const int* in_sizes, int n_in,
                              void* d_out, int out_size, void* d_ws, size_t ws_size,
                              hipStream_t stream) {
    const int*   rels       = (const int*)d_in[0];
    const int*   terms_L    = (const int*)d_in[1];
    const int*   terms_R    = (const int*)d_in[2];
    const float* term_table = (const float*)d_in[3];
    const float* rel_table  = (const float*)d_in[4];
    const float* assoc      = (const float*)d_in[5];
    float* out = (float*)d_out;
    int B = in_sizes[0];

    int* wsi        = (int*)d_ws;
    int* cnt        = wsi;
    int* cursor     = wsi + 64;
    int* n_chunks   = wsi + 128;
    int* desc_rel   = wsi + DESC_OFF;
    int* desc_start = desc_rel + MAX_CHUNKS;
    int* desc_end   = desc_start + MAX_CHUNKS;
    int* sorted     = wsi + SORTED_OFF;
    __hip_bfloat16* Mt = (__hip_bfloat16*)((char*)d_ws + MT_OFF_BYTES(B));

    int nb = (B + 255) / 256;
    k_init<<<1, 128, 0, stream>>>(cnt);
    k_hist<<<nb, 256, 0, stream>>>(rels, B, cnt);
    k_scan<<<1, 256, 0, stream>>>(cnt, cursor, n_chunks, desc_rel, desc_start, desc_end);
    k_scatter<<<nb, 256, 0, stream>>>(rels, B, cursor, sorted);
    k_build_mt<<<NRELS * 100, 256, 0, stream>>>(rel_table, assoc, Mt);
    k_gemm<<<MAX_CHUNKS, 256, 0, stream>>>(sorted, desc_rel, desc_start, desc_end,
                                           n_chunks, terms_L, terms_R, term_table, Mt, out);
}